// Round 3
// baseline (11642.095 us; speedup 1.0000x reference)
//
#include <hip/hip_runtime.h>
#include <math.h>

#define T 2048
#define D 512
#define NH 8
#define DH 64
#define NL 4

typedef float f32x4 __attribute__((ext_vector_type(4)));
typedef short bf16x8 __attribute__((ext_vector_type(8)));

__device__ inline unsigned short f2bf(float x) {
    unsigned int u = __float_as_uint(x);
    unsigned int r = (u + 0x7FFFu + ((u >> 16) & 1u)) >> 16;  // RNE
    return (unsigned short)r;
}

__global__ void add_pos_kernel(const float* __restrict__ seq,
                               const float* __restrict__ pos,
                               float* __restrict__ x, int n) {
    int i = blockIdx.x * blockDim.x + threadIdx.x;
    if (i < n) x[i] = seq[i] + pos[i];
}

// One block (256 threads) per row; D = 512 -> 2 elements per thread.
__global__ __launch_bounds__(256) void layernorm_kernel(
    const float* __restrict__ x, const float* __restrict__ w,
    const float* __restrict__ b, float* __restrict__ out) {
    int row = blockIdx.x;
    int tid = threadIdx.x;
    const float* xr = x + (size_t)row * D;
    float v0 = xr[tid];
    float v1 = xr[tid + 256];
    __shared__ float red[256];
    red[tid] = v0 + v1;
    __syncthreads();
    for (int off = 128; off > 0; off >>= 1) {
        if (tid < off) red[tid] += red[tid + off];
        __syncthreads();
    }
    float mu = red[0] * (1.0f / D);
    __syncthreads();
    float d0 = v0 - mu, d1 = v1 - mu;
    red[tid] = d0 * d0 + d1 * d1;
    __syncthreads();
    for (int off = 128; off > 0; off >>= 1) {
        if (tid < off) red[tid] += red[tid + off];
        __syncthreads();
    }
    float rstd = rsqrtf(red[0] * (1.0f / D) + 1e-5f);
    out[(size_t)row * D + tid]       = d0 * rstd * w[tid]       + b[tid];
    out[(size_t)row * D + tid + 256] = d1 * rstd * w[tid + 256] + b[tid + 256];
}

// C[M,N] = act( A[M,K] @ W[K,N] + bias + resid ), bf16 MFMA compute, fp32 accum.
// 64x64 block tile, BK=32, 256 threads = 4 waves in 2x2; each wave: 2x2 of 16x16 MFMA.
#define GBM 64
#define GBN 64
#define GBK 32
#define LDP 40  // padded K-stride in bf16 elems: 80B = multiple of 16B, spreads banks
__global__ __launch_bounds__(256) void gemm_mfma_kernel(
    const float* __restrict__ A, const float* __restrict__ W,
    const float* __restrict__ bias, const float* __restrict__ resid,
    float* __restrict__ C, int M, int K, int N, int act) {
    __shared__ unsigned short As[GBM][LDP];  // [m][k]
    __shared__ unsigned short Bs[GBN][LDP];  // [n][k]
    int tid = threadIdx.x;
    int lane = tid & 63;
    int w = tid >> 6;
    int wr = w >> 1, wc = w & 1;            // 2x2 wave grid, each 32x32 out
    int rowBase = blockIdx.y * GBM, colBase = blockIdx.x * GBN;

    f32x4 acc[2][2];
    #pragma unroll
    for (int i = 0; i < 2; ++i)
        #pragma unroll
        for (int j = 0; j < 2; ++j)
            acc[i][j] = (f32x4){0.f, 0.f, 0.f, 0.f};

    int half = lane >> 4;      // k-chunk selector (0..3) * 8
    int r16 = lane & 15;       // row (A) / col (B) within 16

    for (int k0 = 0; k0 < K; k0 += GBK) {
        // stage A tile 64x32: thread t -> row t>>2, cols (t&3)*8..+8 (coalesced)
        {
            int r = tid >> 2, c8 = (tid & 3) * 8;
            const float* src = A + (size_t)(rowBase + r) * K + k0 + c8;
            #pragma unroll
            for (int j = 0; j < 8; ++j) As[r][c8 + j] = f2bf(src[j]);
        }
        // stage W tile 32x64 transposed into Bs[n][k]: thread t -> k=t>>3, n=(t&7)*8..+8
        {
            int k = tid >> 3, n8 = (tid & 7) * 8;
            const float* src = W + (size_t)(k0 + k) * N + colBase + n8;
            #pragma unroll
            for (int j = 0; j < 8; ++j) Bs[n8 + j][k] = f2bf(src[j]);
        }
        __syncthreads();
        #pragma unroll
        for (int mi = 0; mi < 2; ++mi) {
            bf16x8 a = *(const bf16x8*)&As[wr * 32 + mi * 16 + r16][half * 8];
            #pragma unroll
            for (int ni = 0; ni < 2; ++ni) {
                bf16x8 b = *(const bf16x8*)&Bs[wc * 32 + ni * 16 + r16][half * 8];
                acc[mi][ni] = __builtin_amdgcn_mfma_f32_16x16x32_bf16(a, b, acc[mi][ni], 0, 0, 0);
            }
        }
        __syncthreads();
    }
    // epilogue: D map col=lane&15, row=(lane>>4)*4+reg  [m89/m91]
    #pragma unroll
    for (int mi = 0; mi < 2; ++mi) {
        #pragma unroll
        for (int ni = 0; ni < 2; ++ni) {
            int col = colBase + wc * 32 + ni * 16 + r16;
            #pragma unroll
            for (int j = 0; j < 4; ++j) {
                int row = rowBase + wr * 32 + mi * 16 + half * 4 + j;
                float v = acc[mi][ni][j];
                if (bias)  v += bias[col];
                if (resid) v += resid[(size_t)row * N + col];
                if (act == 1) v = 0.5f * v * (1.0f + erff(v * 0.70710678118f));
                C[(size_t)row * N + col] = v;
            }
        }
    }
}

// One block per (query, head). Scores row staged in LDS (T floats).
__global__ __launch_bounds__(256) void attn_kernel(
    const float* __restrict__ Q, const float* __restrict__ K,
    const float* __restrict__ V, float* __restrict__ Y) {
    int qi = blockIdx.x;
    int h  = blockIdx.y;
    int tid = threadIdx.x;
    __shared__ float qs[DH];
    __shared__ float s[T];
    __shared__ float red[256];
    if (tid < DH) qs[tid] = Q[(size_t)qi * D + h * DH + tid];
    __syncthreads();
    const float scale = 0.125f;  // 1/sqrt(64)
    float lmax = -1e30f;
    for (int j = tid; j < T; j += 256) {
        const float* kr = K + (size_t)j * D + h * DH;
        float acc = 0.f;
        #pragma unroll
        for (int d = 0; d < DH; ++d) acc += qs[d] * kr[d];
        acc *= scale;
        s[j] = acc;
        lmax = fmaxf(lmax, acc);
    }
    red[tid] = lmax;
    __syncthreads();
    for (int off = 128; off > 0; off >>= 1) {
        if (tid < off) red[tid] = fmaxf(red[tid], red[tid + off]);
        __syncthreads();
    }
    float mx = red[0];
    __syncthreads();
    float lsum = 0.f;
    for (int j = tid; j < T; j += 256) {
        float p = expf(s[j] - mx);
        s[j] = p;
        lsum += p;
    }
    red[tid] = lsum;
    __syncthreads();
    for (int off = 128; off > 0; off >>= 1) {
        if (tid < off) red[tid] += red[tid + off];
        __syncthreads();
    }
    float inv = 1.0f / red[0];
    __syncthreads();
    int d = tid & 63, part = tid >> 6;
    float acc = 0.f;
    for (int j = part * (T / 4); j < (part + 1) * (T / 4); ++j)
        acc += s[j] * V[(size_t)j * D + h * DH + d];
    red[tid] = acc;
    __syncthreads();
    if (tid < 64) {
        float tot = red[tid] + red[tid + 64] + red[tid + 128] + red[tid + 192];
        Y[(size_t)qi * D + h * DH + tid] = tot * inv;
    }
}

extern "C" void kernel_launch(void* const* d_in, const int* in_sizes, int n_in,
                              void* d_out, int out_size, void* d_ws, size_t ws_size,
                              hipStream_t stream) {
    const float* seq  = (const float*)d_in[0];
    const float* pos  = (const float*)d_in[1];
    const float* Wq   = (const float*)d_in[2];
    const float* bq   = (const float*)d_in[3];
    const float* Wk   = (const float*)d_in[4];
    const float* bk   = (const float*)d_in[5];
    const float* Wv   = (const float*)d_in[6];
    const float* bv   = (const float*)d_in[7];
    const float* Wp   = (const float*)d_in[8];
    const float* bp   = (const float*)d_in[9];
    const float* W1   = (const float*)d_in[10];
    const float* b1   = (const float*)d_in[11];
    const float* W2   = (const float*)d_in[12];
    const float* b2   = (const float*)d_in[13];
    const float* ln1w = (const float*)d_in[14];
    const float* ln1b = (const float*)d_in[15];
    const float* ln2w = (const float*)d_in[16];
    const float* ln2b = (const float*)d_in[17];
    const float* lnfw = (const float*)d_in[18];
    const float* lnfb = (const float*)d_in[19];
    const float* Whead = (const float*)d_in[20];
    float* out = (float*)d_out;

    float* ws = (float*)d_ws;
    const size_t SZ = (size_t)T * D;  // 1,048,576 floats
    float* X  = ws;
    float* Hb = ws + SZ;
    float* Qb = ws + 2 * SZ;
    float* Kb = ws + 3 * SZ;
    float* Vb = ws + 4 * SZ;
    float* Yb = ws + 5 * SZ;
    float* M1 = ws + 6 * SZ;  // T x 4D = 4,194,304 floats

    dim3 b256(256);
    add_pos_kernel<<<(T * D + 255) / 256, b256, 0, stream>>>(seq, pos, X, T * D);

    for (int l = 0; l < NL; ++l) {
        layernorm_kernel<<<T, b256, 0, stream>>>(X, ln1w + l * D, ln1b + l * D, Hb);
        gemm_mfma_kernel<<<dim3(D / GBN, T / GBM), b256, 0, stream>>>(
            Hb, Wq + (size_t)l * D * D, bq + l * D, nullptr, Qb, T, D, D, 0);
        gemm_mfma_kernel<<<dim3(D / GBN, T / GBM), b256, 0, stream>>>(
            Hb, Wk + (size_t)l * D * D, bk + l * D, nullptr, Kb, T, D, D, 0);
        gemm_mfma_kernel<<<dim3(D / GBN, T / GBM), b256, 0, stream>>>(
            Hb, Wv + (size_t)l * D * D, bv + l * D, nullptr, Vb, T, D, D, 0);
        attn_kernel<<<dim3(T, NH), b256, 0, stream>>>(Qb, Kb, Vb, Yb);
        gemm_mfma_kernel<<<dim3(D / GBN, T / GBM), b256, 0, stream>>>(
            Yb, Wp + (size_t)l * D * D, bp + l * D, X, X, T, D, D, 0);
        layernorm_kernel<<<T, b256, 0, stream>>>(X, ln2w + l * D, ln2b + l * D, Hb);
        gemm_mfma_kernel<<<dim3(4 * D / GBN, T / GBM), b256, 0, stream>>>(
            Hb, W1 + (size_t)l * D * 4 * D, b1 + l * 4 * D, nullptr, M1, T, D, 4 * D, 1);
        gemm_mfma_kernel<<<dim3(D / GBN, T / GBM), b256, 0, stream>>>(
            M1, W2 + (size_t)l * 4 * D * D, b2 + l * D, X, X, T, 4 * D, D, 0);
    }
    layernorm_kernel<<<T, b256, 0, stream>>>(X, lnfw, lnfb, Hb);
    gemm_mfma_kernel<<<dim3(D / GBN, T / GBM), b256, 0, stream>>>(
        Hb, Whead, nullptr, nullptr, out, T, D, D, 0);
}

// Round 5
// 1362.752 us; speedup vs baseline: 8.5431x; 8.5431x over previous
//
#include <hip/hip_runtime.h>
#include <math.h>

#define T 2048
#define D 512
#define NH 8
#define DH 64
#define NL 4

typedef float f32x4 __attribute__((ext_vector_type(4)));
typedef short bf16x8 __attribute__((ext_vector_type(8)));

__device__ inline unsigned short f2bf(float x) {
    unsigned int u = __float_as_uint(x);
    unsigned int r = (u + 0x7FFFu + ((u >> 16) & 1u)) >> 16;  // RNE
    return (unsigned short)r;
}

__global__ void add_pos_kernel(const float* __restrict__ seq,
                               const float* __restrict__ pos,
                               float* __restrict__ x, int n) {
    int i = blockIdx.x * blockDim.x + threadIdx.x;
    if (i < n) x[i] = seq[i] + pos[i];
}

// One block (256 threads) per row; D = 512 -> 2 elements per thread.
__global__ __launch_bounds__(256) void layernorm_kernel(
    const float* __restrict__ x, const float* __restrict__ w,
    const float* __restrict__ b, float* __restrict__ out) {
    int row = blockIdx.x;
    int tid = threadIdx.x;
    const float* xr = x + (size_t)row * D;
    float v0 = xr[tid];
    float v1 = xr[tid + 256];
    __shared__ float red[256];
    red[tid] = v0 + v1;
    __syncthreads();
    for (int off = 128; off > 0; off >>= 1) {
        if (tid < off) red[tid] += red[tid + off];
        __syncthreads();
    }
    float mu = red[0] * (1.0f / D);
    __syncthreads();
    float d0 = v0 - mu, d1 = v1 - mu;
    red[tid] = d0 * d0 + d1 * d1;
    __syncthreads();
    for (int off = 128; off > 0; off >>= 1) {
        if (tid < off) red[tid] += red[tid + off];
        __syncthreads();
    }
    float rstd = rsqrtf(red[0] * (1.0f / D) + 1e-5f);
    out[(size_t)row * D + tid]       = d0 * rstd * w[tid]       + b[tid];
    out[(size_t)row * D + tid + 256] = d1 * rstd * w[tid + 256] + b[tid + 256];
}

// C[M,N] = act( A[M,K] @ W[K,N] + bias + resid ), bf16 MFMA compute, fp32 accum.
// 64x64 block tile, BK=32, 256 threads = 4 waves in 2x2; each wave: 2x2 of 16x16 MFMA.
#define GBM 64
#define GBN 64
#define GBK 32
#define LDP 40  // padded K-stride in bf16 elems: 80B = multiple of 16B, spreads banks
__global__ __launch_bounds__(256) void gemm_mfma_kernel(
    const float* __restrict__ A, const float* __restrict__ W,
    const float* __restrict__ bias, const float* __restrict__ resid,
    float* __restrict__ C, int M, int K, int N, int act) {
    __shared__ unsigned short As[GBM][LDP];  // [m][k]
    __shared__ unsigned short Bs[GBN][LDP];  // [n][k]
    int tid = threadIdx.x;
    int lane = tid & 63;
    int w = tid >> 6;
    int wr = w >> 1, wc = w & 1;            // 2x2 wave grid, each 32x32 out
    int rowBase = blockIdx.y * GBM, colBase = blockIdx.x * GBN;

    f32x4 acc[2][2];
    #pragma unroll
    for (int i = 0; i < 2; ++i)
        #pragma unroll
        for (int j = 0; j < 2; ++j)
            acc[i][j] = (f32x4){0.f, 0.f, 0.f, 0.f};

    int half = lane >> 4;      // k-chunk selector
    int r16 = lane & 15;       // row (A) / col (B) within 16

    for (int k0 = 0; k0 < K; k0 += GBK) {
        {
            int r = tid >> 2, c8 = (tid & 3) * 8;
            const float* src = A + (size_t)(rowBase + r) * K + k0 + c8;
            #pragma unroll
            for (int j = 0; j < 8; ++j) As[r][c8 + j] = f2bf(src[j]);
        }
        {
            int k = tid >> 3, n8 = (tid & 7) * 8;
            const float* src = W + (size_t)(k0 + k) * N + colBase + n8;
            #pragma unroll
            for (int j = 0; j < 8; ++j) Bs[n8 + j][k] = f2bf(src[j]);
        }
        __syncthreads();
        #pragma unroll
        for (int mi = 0; mi < 2; ++mi) {
            bf16x8 a = *(const bf16x8*)&As[wr * 32 + mi * 16 + r16][half * 8];
            #pragma unroll
            for (int ni = 0; ni < 2; ++ni) {
                bf16x8 b = *(const bf16x8*)&Bs[wc * 32 + ni * 16 + r16][half * 8];
                acc[mi][ni] = __builtin_amdgcn_mfma_f32_16x16x32_bf16(a, b, acc[mi][ni], 0, 0, 0);
            }
        }
        __syncthreads();
    }
    #pragma unroll
    for (int mi = 0; mi < 2; ++mi) {
        #pragma unroll
        for (int ni = 0; ni < 2; ++ni) {
            int col = colBase + wc * 32 + ni * 16 + r16;
            #pragma unroll
            for (int j = 0; j < 4; ++j) {
                int row = rowBase + wr * 32 + mi * 16 + half * 4 + j;
                float v = acc[mi][ni][j];
                if (bias)  v += bias[col];
                if (resid) v += resid[(size_t)row * N + col];
                if (act == 1) v = 0.5f * v * (1.0f + erff(v * 0.70710678118f));
                C[(size_t)row * N + col] = v;
            }
        }
    }
}

// Fused flash attention: one block per (64-query tile, head). 4 waves, wave w
// owns q-rows [w*16, w*16+16) -> online-softmax stats stay wave-local.
#define QBLK 64
#define JBLK 64
#define APAD 72  // bf16 elems per row: 144B, 16B-aligned
__global__ __launch_bounds__(256) void flash_attn_kernel(
    const float* __restrict__ Q, const float* __restrict__ K,
    const float* __restrict__ V, float* __restrict__ Y) {
    __shared__ __align__(16) unsigned short Qs[QBLK][APAD];  // [q][d], pre-scaled
    __shared__ __align__(16) unsigned short Ks[JBLK][APAD];  // [j][d]
    __shared__ __align__(16) unsigned short Vs[DH][APAD];    // [d][j] (transposed)
    __shared__ __align__(16) unsigned short Ps[QBLK][APAD];  // [q][j]
    int h = blockIdx.y;
    int qBase = blockIdx.x * QBLK;
    int tid = threadIdx.x;
    int lane = tid & 63;
    int w = tid >> 6;
    int r16 = lane & 15;
    int half = lane >> 4;

    // stage Q once, pre-scaled by 1/sqrt(DH)=0.125 (power of 2: exact)
    {
        int r = tid >> 2, d0 = (tid & 3) * 16;
        const float* src = Q + (size_t)(qBase + r) * D + h * DH + d0;
        #pragma unroll
        for (int i = 0; i < 16; ++i) Qs[r][d0 + i] = f2bf(src[i] * 0.125f);
    }

    f32x4 o_acc[4];
    #pragma unroll
    for (int i = 0; i < 4; ++i) o_acc[i] = (f32x4){0.f, 0.f, 0.f, 0.f};
    float m_run[4], l_run[4];
    #pragma unroll
    for (int j = 0; j < 4; ++j) { m_run[j] = -3e38f; l_run[j] = 0.f; }

    for (int jt = 0; jt < T / JBLK; ++jt) {
        int jBase = jt * JBLK;
        __syncthreads();  // protect Ks/Vs (and Qs on first iter) from prior readers
        {
            int r = tid >> 2, d0 = (tid & 3) * 16;
            const float* ksrc = K + (size_t)(jBase + r) * D + h * DH + d0;
            const float* vsrc = V + (size_t)(jBase + r) * D + h * DH + d0;
            #pragma unroll
            for (int i = 0; i < 16; ++i) {
                Ks[r][d0 + i] = f2bf(ksrc[i]);
                Vs[d0 + i][r] = f2bf(vsrc[i]);
            }
        }
        __syncthreads();
        // S(16x64) = Q_tile(16xDH) @ K_tile^T : accumulate over DH in 2 k-steps
        f32x4 s[4];
        #pragma unroll
        for (int ni = 0; ni < 4; ++ni) s[ni] = (f32x4){0.f, 0.f, 0.f, 0.f};
        #pragma unroll
        for (int k0 = 0; k0 < 2; ++k0) {
            bf16x8 a = *(const bf16x8*)&Qs[w * 16 + r16][k0 * 32 + half * 8];
            #pragma unroll
            for (int ni = 0; ni < 4; ++ni) {
                bf16x8 b = *(const bf16x8*)&Ks[ni * 16 + r16][k0 * 32 + half * 8];
                s[ni] = __builtin_amdgcn_mfma_f32_16x16x32_bf16(a, b, s[ni], 0, 0, 0);
            }
        }
        // per-row (row = half*4 + j) online softmax; reduce across 16-lane col group
        float alpha[4];
        #pragma unroll
        for (int j = 0; j < 4; ++j) {
            float mx = fmaxf(fmaxf(s[0][j], s[1][j]), fmaxf(s[2][j], s[3][j]));
            #pragma unroll
            for (int msk = 1; msk < 16; msk <<= 1) mx = fmaxf(mx, __shfl_xor(mx, msk));
            float mn = fmaxf(m_run[j], mx);
            alpha[j] = __expf(m_run[j] - mn);
            m_run[j] = mn;
        }
        #pragma unroll
        for (int j = 0; j < 4; ++j) {
            float sum = 0.f;
            #pragma unroll
            for (int ni = 0; ni < 4; ++ni) {
                float p = __expf(s[ni][j] - m_run[j]);
                sum += p;
                Ps[w * 16 + half * 4 + j][ni * 16 + r16] = f2bf(p);
            }
            #pragma unroll
            for (int msk = 1; msk < 16; msk <<= 1) sum += __shfl_xor(sum, msk);
            l_run[j] = l_run[j] * alpha[j] + sum;
            #pragma unroll
            for (int ni = 0; ni < 4; ++ni) o_acc[ni][j] *= alpha[j];
        }
        // PV: O(16xDH) += P(16x64) @ V_tile(64xDH); Ps rows are wave-local,
        // compiler orders the ds_write->ds_read dependency.
        #pragma unroll
        for (int k0 = 0; k0 < 2; ++k0) {
            bf16x8 a = *(const bf16x8*)&Ps[w * 16 + r16][k0 * 32 + half * 8];
            #pragma unroll
            for (int ni = 0; ni < 4; ++ni) {
                bf16x8 b = *(const bf16x8*)&Vs[ni * 16 + r16][k0 * 32 + half * 8];
                o_acc[ni] = __builtin_amdgcn_mfma_f32_16x16x32_bf16(a, b, o_acc[ni], 0, 0, 0);
            }
        }
    }
    #pragma unroll
    for (int j = 0; j < 4; ++j) {
        float inv = 1.0f / l_run[j];
        int row = qBase + w * 16 + half * 4 + j;
        #pragma unroll
        for (int ni = 0; ni < 4; ++ni)
            Y[(size_t)row * D + h * DH + ni * 16 + r16] = o_acc[ni][j] * inv;
    }
}

extern "C" void kernel_launch(void* const* d_in, const int* in_sizes, int n_in,
                              void* d_out, int out_size, void* d_ws, size_t ws_size,
                              hipStream_t stream) {
    const float* seq  = (const float*)d_in[0];
    const float* pos  = (const float*)d_in[1];
    const float* Wq   = (const float*)d_in[2];
    const float* bq   = (const float*)d_in[3];
    const float* Wk   = (const float*)d_in[4];
    const float* bk   = (const float*)d_in[5];
    const float* Wv   = (const float*)d_in[6];
    const float* bv   = (const float*)d_in[7];
    const float* Wp   = (const float*)d_in[8];
    const float* bp   = (const float*)d_in[9];
    const float* W1   = (const float*)d_in[10];
    const float* b1   = (const float*)d_in[11];
    const float* W2   = (const float*)d_in[12];
    const float* b2   = (const float*)d_in[13];
    const float* ln1w = (const float*)d_in[14];
    const float* ln1b = (const float*)d_in[15];
    const float* ln2w = (const float*)d_in[16];
    const float* ln2b = (const float*)d_in[17];
    const float* lnfw = (const float*)d_in[18];
    const float* lnfb = (const float*)d_in[19];
    const float* Whead = (const float*)d_in[20];
    float* out = (float*)d_out;

    float* ws = (float*)d_ws;
    const size_t SZ = (size_t)T * D;  // 1,048,576 floats
    float* X  = ws;
    float* Hb = ws + SZ;
    float* Qb = ws + 2 * SZ;
    float* Kb = ws + 3 * SZ;
    float* Vb = ws + 4 * SZ;
    float* Yb = ws + 5 * SZ;
    float* M1 = ws + 6 * SZ;  // T x 4D = 4,194,304 floats

    dim3 b256(256);
    add_pos_kernel<<<(T * D + 255) / 256, b256, 0, stream>>>(seq, pos, X, T * D);

    for (int l = 0; l < NL; ++l) {
        layernorm_kernel<<<T, b256, 0, stream>>>(X, ln1w + l * D, ln1b + l * D, Hb);
        gemm_mfma_kernel<<<dim3(D / GBN, T / GBM), b256, 0, stream>>>(
            Hb, Wq + (size_t)l * D * D, bq + l * D, nullptr, Qb, T, D, D, 0);
        gemm_mfma_kernel<<<dim3(D / GBN, T / GBM), b256, 0, stream>>>(
            Hb, Wk + (size_t)l * D * D, bk + l * D, nullptr, Kb, T, D, D, 0);
        gemm_mfma_kernel<<<dim3(D / GBN, T / GBM), b256, 0, stream>>>(
            Hb, Wv + (size_t)l * D * D, bv + l * D, nullptr, Vb, T, D, D, 0);
        flash_attn_kernel<<<dim3(T / QBLK, NH), b256, 0, stream>>>(Qb, Kb, Vb, Yb);
        gemm_mfma_kernel<<<dim3(D / GBN, T / GBM), b256, 0, stream>>>(
            Yb, Wp + (size_t)l * D * D, bp + l * D, X, X, T, D, D, 0);
        layernorm_kernel<<<T, b256, 0, stream>>>(X, ln2w + l * D, ln2b + l * D, Hb);
        gemm_mfma_kernel<<<dim3(4 * D / GBN, T / GBM), b256, 0, stream>>>(
            Hb, W1 + (size_t)l * D * 4 * D, b1 + l * 4 * D, nullptr, M1, T, D, 4 * D, 1);
        gemm_mfma_kernel<<<dim3(D / GBN, T / GBM), b256, 0, stream>>>(
            M1, W2 + (size_t)l * 4 * D * D, b2 + l * D, X, X, T, 4 * D, D, 0);
    }
    layernorm_kernel<<<T, b256, 0, stream>>>(X, lnfw, lnfb, Hb);
    gemm_mfma_kernel<<<dim3(D / GBN, T / GBM), b256, 0, stream>>>(
        Hb, Whead, nullptr, nullptr, out, T, D, D, 0);
}

// Round 7
// 904.412 us; speedup vs baseline: 12.8726x; 1.5068x over previous
//
#include <hip/hip_runtime.h>
#include <math.h>

#define T 2048
#define D 512
#define NH 8
#define DH 64
#define NL 4

typedef float f32x4 __attribute__((ext_vector_type(4)));
typedef short bf16x8 __attribute__((ext_vector_type(8)));
typedef unsigned short ushort_t;

#define MODE_F32 0
#define MODE_BF16 1
#define MODE_BF16_GELU 2
#define MODE_BF16_SCALE 3
#define MODE_BF16_T 4

__device__ inline ushort_t f2bf(float x) {
    unsigned int u = __float_as_uint(x);
    unsigned int r = (u + 0x7FFFu + ((u >> 16) & 1u)) >> 16;  // RNE
    return (ushort_t)r;
}

__global__ void add_pos_kernel(const float* __restrict__ seq,
                               const float* __restrict__ pos,
                               float* __restrict__ x, int n) {
    int i = blockIdx.x * blockDim.x + threadIdx.x;
    if (i < n) x[i] = seq[i] + pos[i];
}

// Tiled transpose+convert: W[z][K][N] fp32 -> Wt[z][N][K] bf16.
__global__ __launch_bounds__(256) void wt_kernel(
    const float* __restrict__ W, ushort_t* __restrict__ Wt, int K, int N) {
    __shared__ float tile[32][33];
    int tx = threadIdx.x & 31, ty = threadIdx.x >> 5;  // 32 x 8
    const float* Wz = W + (size_t)blockIdx.z * K * N;
    ushort_t* Wtz = Wt + (size_t)blockIdx.z * K * N;
    int n0 = blockIdx.x * 32, k0 = blockIdx.y * 32;
    #pragma unroll
    for (int i = 0; i < 4; ++i)
        tile[ty + i * 8][tx] = Wz[(size_t)(k0 + ty + i * 8) * N + n0 + tx];
    __syncthreads();
    #pragma unroll
    for (int i = 0; i < 4; ++i)
        Wtz[(size_t)(n0 + ty + i * 8) * K + k0 + tx] = f2bf(tile[tx][ty + i * 8]);
}

// One block (256 threads) per row; writes bf16.
__global__ __launch_bounds__(256) void layernorm_kernel(
    const float* __restrict__ x, const float* __restrict__ w,
    const float* __restrict__ b, ushort_t* __restrict__ out) {
    int row = blockIdx.x;
    int tid = threadIdx.x;
    const float* xr = x + (size_t)row * D;
    float v0 = xr[tid];
    float v1 = xr[tid + 256];
    __shared__ float red[256];
    red[tid] = v0 + v1;
    __syncthreads();
    for (int off = 128; off > 0; off >>= 1) {
        if (tid < off) red[tid] += red[tid + off];
        __syncthreads();
    }
    float mu = red[0] * (1.0f / D);
    __syncthreads();
    float d0 = v0 - mu, d1 = v1 - mu;
    red[tid] = d0 * d0 + d1 * d1;
    __syncthreads();
    for (int off = 128; off > 0; off >>= 1) {
        if (tid < off) red[tid] += red[tid + off];
        __syncthreads();
    }
    float rstd = rsqrtf(red[0] * (1.0f / D) + 1e-5f);
    out[(size_t)row * D + tid]       = f2bf(d0 * rstd * w[tid]       + b[tid]);
    out[(size_t)row * D + tid + 256] = f2bf(d1 * rstd * w[tid + 256] + b[tid + 256]);
}

// C = mode( A[M,K](bf16) @ Wt[N,K](bf16) + bias (+resid) )
// 64x64 tile, BK=32, 4 waves 2x2, each wave 2x2 of 16x16x32 MFMA.
#define GBM 64
#define GBN 64
#define GBK 32
#define LDP 40  // bf16 elems per row: 80B, 16B-aligned
__global__ __launch_bounds__(256) void gemm_bf16_kernel(
    const ushort_t* __restrict__ A, const ushort_t* __restrict__ Wt,
    const float* __restrict__ bias, const float* __restrict__ resid,
    void* __restrict__ Cout, int M, int K, int N, int mode) {
    __shared__ ushort_t As[GBM][LDP];
    __shared__ ushort_t Bs[GBN][LDP];
    int tid = threadIdx.x;
    int lane = tid & 63;
    int w = tid >> 6;
    int wr = w >> 1, wc = w & 1;
    int rowBase = blockIdx.y * GBM, colBase = blockIdx.x * GBN;
    int half = lane >> 4;
    int r16 = lane & 15;
    int sr = tid >> 2, sc8 = (tid & 3) * 8;  // staging: row, col-chunk

    f32x4 acc[2][2];
    #pragma unroll
    for (int i = 0; i < 2; ++i)
        #pragma unroll
        for (int j = 0; j < 2; ++j)
            acc[i][j] = (f32x4){0.f, 0.f, 0.f, 0.f};

    const ushort_t* Arow = A + (size_t)(rowBase + sr) * K + sc8;
    const ushort_t* Brow = Wt + (size_t)(colBase + sr) * K + sc8;

    for (int k0 = 0; k0 < K; k0 += GBK) {
        *(bf16x8*)&As[sr][sc8] = *(const bf16x8*)(Arow + k0);
        *(bf16x8*)&Bs[sr][sc8] = *(const bf16x8*)(Brow + k0);
        __syncthreads();
        #pragma unroll
        for (int mi = 0; mi < 2; ++mi) {
            bf16x8 a = *(const bf16x8*)&As[wr * 32 + mi * 16 + r16][half * 8];
            #pragma unroll
            for (int ni = 0; ni < 2; ++ni) {
                bf16x8 b = *(const bf16x8*)&Bs[wc * 32 + ni * 16 + r16][half * 8];
                acc[mi][ni] = __builtin_amdgcn_mfma_f32_16x16x32_bf16(a, b, acc[mi][ni], 0, 0, 0);
            }
        }
        __syncthreads();
    }
    // C/D map: col=lane&15, row=(lane>>4)*4+reg  [verified]
    #pragma unroll
    for (int mi = 0; mi < 2; ++mi) {
        #pragma unroll
        for (int ni = 0; ni < 2; ++ni) {
            int col = colBase + wc * 32 + ni * 16 + r16;
            float bc = bias ? bias[col] : 0.f;
            #pragma unroll
            for (int j = 0; j < 4; ++j) {
                int row = rowBase + wr * 32 + mi * 16 + half * 4 + j;
                float v = acc[mi][ni][j] + bc;
                if (mode == MODE_F32) {
                    if (resid) v += resid[(size_t)row * N + col];
                    ((float*)Cout)[(size_t)row * N + col] = v;
                } else if (mode == MODE_BF16) {
                    ((ushort_t*)Cout)[(size_t)row * N + col] = f2bf(v);
                } else if (mode == MODE_BF16_GELU) {
                    v = 0.5f * v * (1.0f + erff(v * 0.70710678118f));
                    ((ushort_t*)Cout)[(size_t)row * N + col] = f2bf(v);
                } else if (mode == MODE_BF16_SCALE) {
                    ((ushort_t*)Cout)[(size_t)row * N + col] = f2bf(v * 0.125f);
                } else {  // MODE_BF16_T: C^T[col][row], stride M
                    ((ushort_t*)Cout)[(size_t)col * M + row] = f2bf(v);
                }
            }
        }
    }
}

// Fused flash attention, all-bf16 inputs. One block per (64-query tile, head).
// Q pre-scaled by 0.125; V supplied transposed Vt[h*DH+d][T].
#define QBLK 64
#define JBLK 64
#define APAD 72  // bf16 elems per row: 144B, 16B-aligned
__global__ __launch_bounds__(256) void flash_attn_kernel(
    const ushort_t* __restrict__ Q, const ushort_t* __restrict__ Kb,
    const ushort_t* __restrict__ Vt, ushort_t* __restrict__ Y) {
    __shared__ __align__(16) ushort_t Qs[QBLK][APAD];  // [q][d]
    __shared__ __align__(16) ushort_t Ks[JBLK][APAD];  // [j][d]
    __shared__ __align__(16) ushort_t Vs[DH][APAD];    // [d][j]
    __shared__ __align__(16) ushort_t Ps[QBLK][APAD];  // [q][j]
    int h = blockIdx.y;
    int qBase = blockIdx.x * QBLK;
    int tid = threadIdx.x;
    int lane = tid & 63;
    int w = tid >> 6;
    int r16 = lane & 15;
    int half = lane >> 4;
    int sr = tid >> 2, sc16 = (tid & 3) * 16;  // staging: row, col-chunk(16)

    {
        const ushort_t* src = Q + (size_t)(qBase + sr) * D + h * DH + sc16;
        *(bf16x8*)&Qs[sr][sc16]     = *(const bf16x8*)src;
        *(bf16x8*)&Qs[sr][sc16 + 8] = *(const bf16x8*)(src + 8);
    }

    f32x4 o_acc[4];
    #pragma unroll
    for (int i = 0; i < 4; ++i) o_acc[i] = (f32x4){0.f, 0.f, 0.f, 0.f};
    float m_run[4], l_run[4];
    #pragma unroll
    for (int j = 0; j < 4; ++j) { m_run[j] = -3e38f; l_run[j] = 0.f; }

    for (int jt = 0; jt < T / JBLK; ++jt) {
        int jBase = jt * JBLK;
        __syncthreads();  // Qs ready (first iter); Ks/Vs consumers done (later iters)
        {
            const ushort_t* ksrc = Kb + (size_t)(jBase + sr) * D + h * DH + sc16;
            const ushort_t* vsrc = Vt + (size_t)(h * DH + sr) * T + jBase + sc16;
            *(bf16x8*)&Ks[sr][sc16]     = *(const bf16x8*)ksrc;
            *(bf16x8*)&Ks[sr][sc16 + 8] = *(const bf16x8*)(ksrc + 8);
            *(bf16x8*)&Vs[sr][sc16]     = *(const bf16x8*)vsrc;
            *(bf16x8*)&Vs[sr][sc16 + 8] = *(const bf16x8*)(vsrc + 8);
        }
        __syncthreads();
        // S(16x64) = Q_tile @ K_tile^T, 2 k-steps over DH
        f32x4 s[4];
        #pragma unroll
        for (int ni = 0; ni < 4; ++ni) s[ni] = (f32x4){0.f, 0.f, 0.f, 0.f};
        #pragma unroll
        for (int k0 = 0; k0 < 2; ++k0) {
            bf16x8 a = *(const bf16x8*)&Qs[w * 16 + r16][k0 * 32 + half * 8];
            #pragma unroll
            for (int ni = 0; ni < 4; ++ni) {
                bf16x8 b = *(const bf16x8*)&Ks[ni * 16 + r16][k0 * 32 + half * 8];
                s[ni] = __builtin_amdgcn_mfma_f32_16x16x32_bf16(a, b, s[ni], 0, 0, 0);
            }
        }
        float alpha[4];
        #pragma unroll
        for (int j = 0; j < 4; ++j) {
            float mx = fmaxf(fmaxf(s[0][j], s[1][j]), fmaxf(s[2][j], s[3][j]));
            #pragma unroll
            for (int msk = 1; msk < 16; msk <<= 1) mx = fmaxf(mx, __shfl_xor(mx, msk));
            float mn = fmaxf(m_run[j], mx);
            alpha[j] = __expf(m_run[j] - mn);
            m_run[j] = mn;
        }
        #pragma unroll
        for (int j = 0; j < 4; ++j) {
            float sum = 0.f;
            #pragma unroll
            for (int ni = 0; ni < 4; ++ni) {
                float p = __expf(s[ni][j] - m_run[j]);
                sum += p;
                Ps[w * 16 + half * 4 + j][ni * 16 + r16] = f2bf(p);
            }
            #pragma unroll
            for (int msk = 1; msk < 16; msk <<= 1) sum += __shfl_xor(sum, msk);
            l_run[j] = l_run[j] * alpha[j] + sum;
            #pragma unroll
            for (int ni = 0; ni < 4; ++ni) o_acc[ni][j] *= alpha[j];
        }
        // PV: O += P(16x64) @ V(64xDH); B-frag from Vs[d][j] rows
        #pragma unroll
        for (int k0 = 0; k0 < 2; ++k0) {
            bf16x8 a = *(const bf16x8*)&Ps[w * 16 + r16][k0 * 32 + half * 8];
            #pragma unroll
            for (int ni = 0; ni < 4; ++ni) {
                bf16x8 b = *(const bf16x8*)&Vs[ni * 16 + r16][k0 * 32 + half * 8];
                o_acc[ni] = __builtin_amdgcn_mfma_f32_16x16x32_bf16(a, b, o_acc[ni], 0, 0, 0);
            }
        }
    }
    #pragma unroll
    for (int j = 0; j < 4; ++j) {
        float inv = 1.0f / l_run[j];
        int row = qBase + w * 16 + half * 4 + j;
        #pragma unroll
        for (int ni = 0; ni < 4; ++ni)
            Y[(size_t)row * D + h * DH + ni * 16 + r16] = f2bf(o_acc[ni][j] * inv);
    }
}

extern "C" void kernel_launch(void* const* d_in, const int* in_sizes, int n_in,
                              void* d_out, int out_size, void* d_ws, size_t ws_size,
                              hipStream_t stream) {
    const float* seq  = (const float*)d_in[0];
    const float* pos  = (const float*)d_in[1];
    const float* Wq   = (const float*)d_in[2];
    const float* bq   = (const float*)d_in[3];
    const float* Wk   = (const float*)d_in[4];
    const float* bk   = (const float*)d_in[5];
    const float* Wv   = (const float*)d_in[6];
    const float* bv   = (const float*)d_in[7];
    const float* Wp   = (const float*)d_in[8];
    const float* bp   = (const float*)d_in[9];
    const float* W1   = (const float*)d_in[10];
    const float* b1   = (const float*)d_in[11];
    const float* W2   = (const float*)d_in[12];
    const float* b2   = (const float*)d_in[13];
    const float* ln1w = (const float*)d_in[14];
    const float* ln1b = (const float*)d_in[15];
    const float* ln2w = (const float*)d_in[16];
    const float* ln2b = (const float*)d_in[17];
    const float* lnfw = (const float*)d_in[18];
    const float* lnfb = (const float*)d_in[19];
    const float* Whead = (const float*)d_in[20];
    float* out = (float*)d_out;

    float* ws = (float*)d_ws;
    const size_t SZ = (size_t)T * D;       // 1,048,576 (floats)
    const size_t HS = SZ / 2;              // bf16 T*D buffer in float units
    float*    X    = ws;                                    // [0, SZ)
    ushort_t* Hb   = (ushort_t*)(ws + SZ);                  // [SZ, 1.5SZ)
    ushort_t* Qb   = (ushort_t*)(ws + SZ + HS);             // [1.5, 2.0)
    ushort_t* Kb   = (ushort_t*)(ws + SZ + 2 * HS);         // [2.0, 2.5)
    ushort_t* Vt   = (ushort_t*)(ws + SZ + 3 * HS);         // [2.5, 3.0)
    ushort_t* Yb   = (ushort_t*)(ws + SZ + 4 * HS);         // [3.0, 3.5)
    ushort_t* M1   = Qb;  // aliases Qb..Yb (dead when M1 is written) [1.5, 3.5)
    ushort_t* WqT  = (ushort_t*)(ws + SZ + 5 * HS);         // [3.5, 4.0)
    ushort_t* WkT  = (ushort_t*)(ws + SZ + 6 * HS);         // [4.0, 4.5)
    ushort_t* WvT  = (ushort_t*)(ws + SZ + 7 * HS);         // [4.5, 5.0)
    ushort_t* WpT  = (ushort_t*)(ws + SZ + 8 * HS);         // [5.0, 5.5)
    ushort_t* W1T  = (ushort_t*)(ws + SZ + 9 * HS);         // [5.5, 7.5)
    ushort_t* W2T  = (ushort_t*)(ws + SZ + 13 * HS);        // [7.5, 9.5)
    ushort_t* WhT  = (ushort_t*)(ws + SZ + 17 * HS);        // [9.5, 9.625)

    dim3 b256(256);
    // weight transpose+convert (runs every launch; ws is re-poisoned)
    wt_kernel<<<dim3(D / 32, D / 32, NL), b256, 0, stream>>>(Wq, WqT, D, D);
    wt_kernel<<<dim3(D / 32, D / 32, NL), b256, 0, stream>>>(Wk, WkT, D, D);
    wt_kernel<<<dim3(D / 32, D / 32, NL), b256, 0, stream>>>(Wv, WvT, D, D);
    wt_kernel<<<dim3(D / 32, D / 32, NL), b256, 0, stream>>>(Wp, WpT, D, D);
    wt_kernel<<<dim3(4 * D / 32, D / 32, NL), b256, 0, stream>>>(W1, W1T, D, 4 * D);
    wt_kernel<<<dim3(D / 32, 4 * D / 32, NL), b256, 0, stream>>>(W2, W2T, 4 * D, D);
    wt_kernel<<<dim3(D / 32, D / 32, 1), b256, 0, stream>>>(Whead, WhT, D, D);

    add_pos_kernel<<<(T * D + 255) / 256, b256, 0, stream>>>(seq, pos, X, T * D);

    for (int l = 0; l < NL; ++l) {
        size_t wo = (size_t)l * D * D;       // per-layer offset in D*D weights
        size_t wo1 = (size_t)l * D * 4 * D;  // per-layer offset in D*4D weights
        layernorm_kernel<<<T, b256, 0, stream>>>(X, ln1w + l * D, ln1b + l * D, Hb);
        gemm_bf16_kernel<<<dim3(D / GBN, T / GBM), b256, 0, stream>>>(
            Hb, WqT + wo, bq + l * D, nullptr, Qb, T, D, D, MODE_BF16_SCALE);
        gemm_bf16_kernel<<<dim3(D / GBN, T / GBM), b256, 0, stream>>>(
            Hb, WkT + wo, bk + l * D, nullptr, Kb, T, D, D, MODE_BF16);
        gemm_bf16_kernel<<<dim3(D / GBN, T / GBM), b256, 0, stream>>>(
            Hb, WvT + wo, bv + l * D, nullptr, Vt, T, D, D, MODE_BF16_T);
        flash_attn_kernel<<<dim3(T / QBLK, NH), b256, 0, stream>>>(Qb, Kb, Vt, Yb);
        gemm_bf16_kernel<<<dim3(D / GBN, T / GBM), b256, 0, stream>>>(
            Yb, WpT + wo, bp + l * D, X, X, T, D, D, MODE_F32);
        layernorm_kernel<<<T, b256, 0, stream>>>(X, ln2w + l * D, ln2b + l * D, Hb);
        gemm_bf16_kernel<<<dim3(4 * D / GBN, T / GBM), b256, 0, stream>>>(
            Hb, W1T + wo1, b1 + l * 4 * D, nullptr, M1, T, D, 4 * D, MODE_BF16_GELU);
        gemm_bf16_kernel<<<dim3(D / GBN, T / GBM), b256, 0, stream>>>(
            M1, W2T + wo1, b2 + l * D, X, X, T, 4 * D, D, MODE_F32);
    }
    layernorm_kernel<<<T, b256, 0, stream>>>(X, lnfw, lnfb, Hb);
    gemm_bf16_kernel<<<dim3(D / GBN, T / GBM), b256, 0, stream>>>(
        Hb, WhT, nullptr, nullptr, out, T, D, D, MODE_F32);
}

// Round 9
// 583.988 us; speedup vs baseline: 19.9355x; 1.5487x over previous
//
#include <hip/hip_runtime.h>
#include <math.h>

#define T 2048
#define D 512
#define NH 8
#define DH 64
#define NL 4

typedef float f32x4 __attribute__((ext_vector_type(4)));
typedef short bf16x8 __attribute__((ext_vector_type(8)));
typedef unsigned short u16x4 __attribute__((ext_vector_type(4)));
typedef unsigned short ushort_t;

#define MODE_F32 0
#define MODE_BF16_GELU 1

__device__ inline ushort_t f2bf(float x) {
    unsigned int u = __float_as_uint(x);
    unsigned int r = (u + 0x7FFFu + ((u >> 16) & 1u)) >> 16;  // RNE
    return (ushort_t)r;
}

__global__ void add_pos_kernel(const float* __restrict__ seq,
                               const float* __restrict__ pos,
                               float* __restrict__ x, int n) {
    int i = blockIdx.x * blockDim.x + threadIdx.x;
    if (i < n) x[i] = seq[i] + pos[i];
}

// Tiled transpose+convert: W[z·wZ + K×N] fp32 -> Wt[z·dZ + N×K] bf16.
__global__ __launch_bounds__(256) void wt_kernel(
    const float* __restrict__ W, ushort_t* __restrict__ Wt, int K, int N,
    size_t wZ, size_t dZ) {
    __shared__ float tile[32][33];
    int tx = threadIdx.x & 31, ty = threadIdx.x >> 5;  // 32 x 8
    const float* Wz = W + (size_t)blockIdx.z * wZ;
    ushort_t* Wtz = Wt + (size_t)blockIdx.z * dZ;
    int n0 = blockIdx.x * 32, k0 = blockIdx.y * 32;
    #pragma unroll
    for (int i = 0; i < 4; ++i)
        tile[ty + i * 8][tx] = Wz[(size_t)(k0 + ty + i * 8) * N + n0 + tx];
    __syncthreads();
    #pragma unroll
    for (int i = 0; i < 4; ++i)
        Wtz[(size_t)(n0 + ty + i * 8) * K + k0 + tx] = f2bf(tile[tx][ty + i * 8]);
}

// One block (256 threads) per row; writes bf16.
__global__ __launch_bounds__(256) void layernorm_kernel(
    const float* __restrict__ x, const float* __restrict__ w,
    const float* __restrict__ b, ushort_t* __restrict__ out) {
    int row = blockIdx.x;
    int tid = threadIdx.x;
    const float* xr = x + (size_t)row * D;
    float v0 = xr[tid];
    float v1 = xr[tid + 256];
    __shared__ float red[256];
    red[tid] = v0 + v1;
    __syncthreads();
    for (int off = 128; off > 0; off >>= 1) {
        if (tid < off) red[tid] += red[tid + off];
        __syncthreads();
    }
    float mu = red[0] * (1.0f / D);
    __syncthreads();
    float d0 = v0 - mu, d1 = v1 - mu;
    red[tid] = d0 * d0 + d1 * d1;
    __syncthreads();
    for (int off = 128; off > 0; off >>= 1) {
        if (tid < off) red[tid] += red[tid + off];
        __syncthreads();
    }
    float rstd = rsqrtf(red[0] * (1.0f / D) + 1e-5f);
    out[(size_t)row * D + tid]       = f2bf(d0 * rstd * w[tid]       + b[tid]);
    out[(size_t)row * D + tid + 256] = f2bf(d1 * rstd * w[tid + 256] + b[tid + 256]);
}

// Generic GEMM: C = mode( A[M,K](bf16) @ Wt[N,K](bf16) + bias (+resid) )
// 64x64 tile, BK=64, double-buffered LDS, 1 barrier/iter, reg prefetch.
#define GBM 64
#define GBN 64
#define GBK 64
#define LDG 72  // bf16 elems per row: 144B, 16B-aligned
__global__ __launch_bounds__(256) void gemm_bf16_kernel(
    const ushort_t* __restrict__ A, const ushort_t* __restrict__ Wt,
    const float* __restrict__ bias, const float* __restrict__ resid,
    void* __restrict__ Cout, int M, int K, int N, int mode) {
    __shared__ __align__(16) ushort_t As[2][GBM][LDG];
    __shared__ __align__(16) ushort_t Bs[2][GBN][LDG];
    int tid = threadIdx.x;
    int lane = tid & 63;
    int w = tid >> 6;
    int wr = w >> 1, wc = w & 1;
    int rowBase = blockIdx.y * GBM, colBase = blockIdx.x * GBN;
    int half = lane >> 4;
    int r16 = lane & 15;
    int sr = tid >> 2, sc = (tid & 3) * 16;

    const ushort_t* Arow = A + (size_t)(rowBase + sr) * K + sc;
    const ushort_t* Brow = Wt + (size_t)(colBase + sr) * K + sc;
    bf16x8 a0 = *(const bf16x8*)Arow, a1 = *(const bf16x8*)(Arow + 8);
    bf16x8 b0 = *(const bf16x8*)Brow, b1 = *(const bf16x8*)(Brow + 8);

    f32x4 acc[2][2];
    #pragma unroll
    for (int i = 0; i < 2; ++i)
        #pragma unroll
        for (int j = 0; j < 2; ++j)
            acc[i][j] = (f32x4){0.f, 0.f, 0.f, 0.f};

    int nIter = K / GBK;
    for (int it = 0; it < nIter; ++it) {
        int buf = it & 1;
        *(bf16x8*)&As[buf][sr][sc]     = a0;
        *(bf16x8*)&As[buf][sr][sc + 8] = a1;
        *(bf16x8*)&Bs[buf][sr][sc]     = b0;
        *(bf16x8*)&Bs[buf][sr][sc + 8] = b1;
        __syncthreads();
        if (it + 1 < nIter) {
            const ushort_t* An = Arow + (it + 1) * GBK;
            const ushort_t* Bn = Brow + (it + 1) * GBK;
            a0 = *(const bf16x8*)An; a1 = *(const bf16x8*)(An + 8);
            b0 = *(const bf16x8*)Bn; b1 = *(const bf16x8*)(Bn + 8);
        }
        #pragma unroll
        for (int ks = 0; ks < 2; ++ks)
            #pragma unroll
            for (int mi = 0; mi < 2; ++mi) {
                bf16x8 af = *(const bf16x8*)&As[buf][wr * 32 + mi * 16 + r16][ks * 32 + half * 8];
                #pragma unroll
                for (int ni = 0; ni < 2; ++ni) {
                    bf16x8 bfv = *(const bf16x8*)&Bs[buf][wc * 32 + ni * 16 + r16][ks * 32 + half * 8];
                    acc[mi][ni] = __builtin_amdgcn_mfma_f32_16x16x32_bf16(af, bfv, acc[mi][ni], 0, 0, 0);
                }
            }
        // no trailing barrier: next iter writes the other buffer; its prior
        // readers (iter-2) all finished before the iter-1 barrier.
    }
    // C/D map: col=lane&15, row=(lane>>4)*4+reg  [verified]
    #pragma unroll
    for (int mi = 0; mi < 2; ++mi) {
        #pragma unroll
        for (int ni = 0; ni < 2; ++ni) {
            int col = colBase + wc * 32 + ni * 16 + r16;
            float bc = bias ? bias[col] : 0.f;
            #pragma unroll
            for (int j = 0; j < 4; ++j) {
                int row = rowBase + wr * 32 + mi * 16 + half * 4 + j;
                float v = acc[mi][ni][j] + bc;
                if (mode == MODE_F32) {
                    if (resid) v += resid[(size_t)row * N + col];
                    ((float*)Cout)[(size_t)row * N + col] = v;
                } else {  // MODE_BF16_GELU
                    v = 0.5f * v * (1.0f + erff(v * 0.70710678118f));
                    ((ushort_t*)Cout)[(size_t)row * N + col] = f2bf(v);
                }
            }
        }
    }
}

// Fused QKV GEMM: A[T,512] @ Wqkv^T[1536,512] + bias, segmented epilogue:
// cols 0-511 -> Q (x0.125, bf16), 512-1023 -> K (bf16), 1024-1535 -> V^T.
__global__ __launch_bounds__(256) void gemm_qkv_kernel(
    const ushort_t* __restrict__ A, const ushort_t* __restrict__ Wt,
    const float* __restrict__ bq, const float* __restrict__ bk,
    const float* __restrict__ bv, ushort_t* __restrict__ Qb,
    ushort_t* __restrict__ Kb, ushort_t* __restrict__ Vt) {
    __shared__ __align__(16) ushort_t As[2][GBM][LDG];
    __shared__ __align__(16) ushort_t Bs[2][GBN][LDG];
    int tid = threadIdx.x;
    int lane = tid & 63;
    int w = tid >> 6;
    int wr = w >> 1, wc = w & 1;
    int rowBase = blockIdx.y * GBM, colBase = blockIdx.x * GBN;
    int half = lane >> 4;
    int r16 = lane & 15;
    int sr = tid >> 2, sc = (tid & 3) * 16;

    const ushort_t* Arow = A + (size_t)(rowBase + sr) * D + sc;
    const ushort_t* Brow = Wt + (size_t)(colBase + sr) * D + sc;
    bf16x8 a0 = *(const bf16x8*)Arow, a1 = *(const bf16x8*)(Arow + 8);
    bf16x8 b0 = *(const bf16x8*)Brow, b1 = *(const bf16x8*)(Brow + 8);

    f32x4 acc[2][2];
    #pragma unroll
    for (int i = 0; i < 2; ++i)
        #pragma unroll
        for (int j = 0; j < 2; ++j)
            acc[i][j] = (f32x4){0.f, 0.f, 0.f, 0.f};

    const int nIter = D / GBK;  // 8
    for (int it = 0; it < nIter; ++it) {
        int buf = it & 1;
        *(bf16x8*)&As[buf][sr][sc]     = a0;
        *(bf16x8*)&As[buf][sr][sc + 8] = a1;
        *(bf16x8*)&Bs[buf][sr][sc]     = b0;
        *(bf16x8*)&Bs[buf][sr][sc + 8] = b1;
        __syncthreads();
        if (it + 1 < nIter) {
            const ushort_t* An = Arow + (it + 1) * GBK;
            const ushort_t* Bn = Brow + (it + 1) * GBK;
            a0 = *(const bf16x8*)An; a1 = *(const bf16x8*)(An + 8);
            b0 = *(const bf16x8*)Bn; b1 = *(const bf16x8*)(Bn + 8);
        }
        #pragma unroll
        for (int ks = 0; ks < 2; ++ks)
            #pragma unroll
            for (int mi = 0; mi < 2; ++mi) {
                bf16x8 af = *(const bf16x8*)&As[buf][wr * 32 + mi * 16 + r16][ks * 32 + half * 8];
                #pragma unroll
                for (int ni = 0; ni < 2; ++ni) {
                    bf16x8 bfv = *(const bf16x8*)&Bs[buf][wc * 32 + ni * 16 + r16][ks * 32 + half * 8];
                    acc[mi][ni] = __builtin_amdgcn_mfma_f32_16x16x32_bf16(af, bfv, acc[mi][ni], 0, 0, 0);
                }
            }
    }
    int seg = colBase >> 9;          // 0:Q 1:K 2:V (block-uniform)
    int lcolB = (colBase & 511) + wc * 32;
    #pragma unroll
    for (int mi = 0; mi < 2; ++mi) {
        #pragma unroll
        for (int ni = 0; ni < 2; ++ni) {
            int col = lcolB + ni * 16 + r16;
            int row0 = rowBase + wr * 32 + mi * 16 + half * 4;
            if (seg == 0) {
                float bc = bq[col];
                #pragma unroll
                for (int j = 0; j < 4; ++j)
                    Qb[(size_t)(row0 + j) * D + col] = f2bf((acc[mi][ni][j] + bc) * 0.125f);
            } else if (seg == 1) {
                float bc = bk[col];
                #pragma unroll
                for (int j = 0; j < 4; ++j)
                    Kb[(size_t)(row0 + j) * D + col] = f2bf(acc[mi][ni][j] + bc);
            } else {
                float bc = bv[col];
                u16x4 p;
                #pragma unroll
                for (int j = 0; j < 4; ++j) p[j] = f2bf(acc[mi][ni][j] + bc);
                *(u16x4*)&Vt[(size_t)col * T + row0] = p;
            }
        }
    }
}

// Fused flash attention, all-bf16, double-buffered K/V prefetch.
// One block per (64-query tile, head); wave w owns q-rows [w*16, w*16+16).
#define QBLK 64
#define JBLK 64
#define APAD 72
__global__ __launch_bounds__(256) void flash_attn_kernel(
    const ushort_t* __restrict__ Q, const ushort_t* __restrict__ Kb,
    const ushort_t* __restrict__ Vt, ushort_t* __restrict__ Y) {
    __shared__ __align__(16) ushort_t Qs[QBLK][APAD];     // [q][d]
    __shared__ __align__(16) ushort_t Ks[2][JBLK][APAD];  // [j][d]
    __shared__ __align__(16) ushort_t Vs[2][DH][APAD];    // [d][j]
    __shared__ __align__(16) ushort_t Ps[QBLK][APAD];     // [q][j]
    int h = blockIdx.y;
    int qBase = blockIdx.x * QBLK;
    int tid = threadIdx.x;
    int lane = tid & 63;
    int w = tid >> 6;
    int r16 = lane & 15;
    int half = lane >> 4;
    int sr = tid >> 2, sc16 = (tid & 3) * 16;

    {
        const ushort_t* src = Q + (size_t)(qBase + sr) * D + h * DH + sc16;
        *(bf16x8*)&Qs[sr][sc16]     = *(const bf16x8*)src;
        *(bf16x8*)&Qs[sr][sc16 + 8] = *(const bf16x8*)(src + 8);
    }
    // prefetch tile 0
    bf16x8 kr0, kr1, vr0, vr1;
    {
        const ushort_t* ks_ = Kb + (size_t)sr * D + h * DH + sc16;
        const ushort_t* vs_ = Vt + (size_t)(h * DH + sr) * T + sc16;
        kr0 = *(const bf16x8*)ks_; kr1 = *(const bf16x8*)(ks_ + 8);
        vr0 = *(const bf16x8*)vs_; vr1 = *(const bf16x8*)(vs_ + 8);
    }

    f32x4 o_acc[4];
    #pragma unroll
    for (int i = 0; i < 4; ++i) o_acc[i] = (f32x4){0.f, 0.f, 0.f, 0.f};
    float m_run[4], l_run[4];
    #pragma unroll
    for (int j = 0; j < 4; ++j) { m_run[j] = -3e38f; l_run[j] = 0.f; }

    const int NT = T / JBLK;
    for (int jt = 0; jt < NT; ++jt) {
        int buf = jt & 1;
        *(bf16x8*)&Ks[buf][sr][sc16]     = kr0;
        *(bf16x8*)&Ks[buf][sr][sc16 + 8] = kr1;
        *(bf16x8*)&Vs[buf][sr][sc16]     = vr0;
        *(bf16x8*)&Vs[buf][sr][sc16 + 8] = vr1;
        __syncthreads();
        if (jt + 1 < NT) {
            int jB = (jt + 1) * JBLK;
            const ushort_t* ks_ = Kb + (size_t)(jB + sr) * D + h * DH + sc16;
            const ushort_t* vs_ = Vt + (size_t)(h * DH + sr) * T + jB + sc16;
            kr0 = *(const bf16x8*)ks_; kr1 = *(const bf16x8*)(ks_ + 8);
            vr0 = *(const bf16x8*)vs_; vr1 = *(const bf16x8*)(vs_ + 8);
        }
        // S(16x64) = Q_tile @ K_tile^T
        f32x4 s[4];
        #pragma unroll
        for (int ni = 0; ni < 4; ++ni) s[ni] = (f32x4){0.f, 0.f, 0.f, 0.f};
        #pragma unroll
        for (int k0 = 0; k0 < 2; ++k0) {
            bf16x8 a = *(const bf16x8*)&Qs[w * 16 + r16][k0 * 32 + half * 8];
            #pragma unroll
            for (int ni = 0; ni < 4; ++ni) {
                bf16x8 b = *(const bf16x8*)&Ks[buf][ni * 16 + r16][k0 * 32 + half * 8];
                s[ni] = __builtin_amdgcn_mfma_f32_16x16x32_bf16(a, b, s[ni], 0, 0, 0);
            }
        }
        float alpha[4];
        #pragma unroll
        for (int j = 0; j < 4; ++j) {
            float mx = fmaxf(fmaxf(s[0][j], s[1][j]), fmaxf(s[2][j], s[3][j]));
            #pragma unroll
            for (int msk = 1; msk < 16; msk <<= 1) mx = fmaxf(mx, __shfl_xor(mx, msk));
            float mn = fmaxf(m_run[j], mx);
            alpha[j] = __expf(m_run[j] - mn);
            m_run[j] = mn;
        }
        #pragma unroll
        for (int j = 0; j < 4; ++j) {
            float sum = 0.f;
            #pragma unroll
            for (int ni = 0; ni < 4; ++ni) {
                float p = __expf(s[ni][j] - m_run[j]);
                sum += p;
                Ps[w * 16 + half * 4 + j][ni * 16 + r16] = f2bf(p);
            }
            #pragma unroll
            for (int msk = 1; msk < 16; msk <<= 1) sum += __shfl_xor(sum, msk);
            l_run[j] = l_run[j] * alpha[j] + sum;
            #pragma unroll
            for (int ni = 0; ni < 4; ++ni) o_acc[ni][j] *= alpha[j];
        }
        // PV: O += P(16x64) @ V(64xDH)
        #pragma unroll
        for (int k0 = 0; k0 < 2; ++k0) {
            bf16x8 a = *(const bf16x8*)&Ps[w * 16 + r16][k0 * 32 + half * 8];
            #pragma unroll
            for (int ni = 0; ni < 4; ++ni) {
                bf16x8 b = *(const bf16x8*)&Vs[buf][ni * 16 + r16][k0 * 32 + half * 8];
                o_acc[ni] = __builtin_amdgcn_mfma_f32_16x16x32_bf16(a, b, o_acc[ni], 0, 0, 0);
            }
        }
    }
    #pragma unroll
    for (int j = 0; j < 4; ++j) {
        float inv = 1.0f / l_run[j];
        int row = qBase + w * 16 + half * 4 + j;
        #pragma unroll
        for (int ni = 0; ni < 4; ++ni)
            Y[(size_t)row * D + h * DH + ni * 16 + r16] = f2bf(o_acc[ni][j] * inv);
    }
}

extern "C" void kernel_launch(void* const* d_in, const int* in_sizes, int n_in,
                              void* d_out, int out_size, void* d_ws, size_t ws_size,
                              hipStream_t stream) {
    const float* seq  = (const float*)d_in[0];
    const float* pos  = (const float*)d_in[1];
    const float* Wq   = (const float*)d_in[2];
    const float* bq   = (const float*)d_in[3];
    const float* Wk   = (const float*)d_in[4];
    const float* bk   = (const float*)d_in[5];
    const float* Wv   = (const float*)d_in[6];
    const float* bv   = (const float*)d_in[7];
    const float* Wp   = (const float*)d_in[8];
    const float* bp   = (const float*)d_in[9];
    const float* W1   = (const float*)d_in[10];
    const float* b1   = (const float*)d_in[11];
    const float* W2   = (const float*)d_in[12];
    const float* b2   = (const float*)d_in[13];
    const float* ln1w = (const float*)d_in[14];
    const float* ln1b = (const float*)d_in[15];
    const float* ln2w = (const float*)d_in[16];
    const float* ln2b = (const float*)d_in[17];
    const float* lnfw = (const float*)d_in[18];
    const float* lnfb = (const float*)d_in[19];
    const float* Whead = (const float*)d_in[20];
    float* out = (float*)d_out;

    float* ws = (float*)d_ws;
    const size_t SZ = (size_t)T * D;   // 1,048,576 floats
    const size_t HS = SZ / 2;          // one bf16 T*D buffer, in float units
    float*    X     = ws;                               // [0, SZ)
    ushort_t* Hb    = (ushort_t*)(ws + SZ);             // +HS
    ushort_t* Qb    = (ushort_t*)(ws + SZ + HS);        // +HS
    ushort_t* Kb    = (ushort_t*)(ws + SZ + 2 * HS);    // +HS
    ushort_t* Vt    = (ushort_t*)(ws + SZ + 3 * HS);    // +HS
    ushort_t* Yb    = (ushort_t*)(ws + SZ + 4 * HS);    // +HS
    ushort_t* M1    = Qb;  // T x 4D bf16, aliases Qb..Yb (dead by then)
    ushort_t* WqkvT = (ushort_t*)(ws + SZ + 5 * HS);    // NL*1536*512 bf16 = 3HS
    ushort_t* WpT   = (ushort_t*)(ws + SZ + 8 * HS);    // NL*D*D bf16 = 1HS
    ushort_t* W1T   = (ushort_t*)(ws + SZ + 9 * HS);    // NL*D*4D bf16 = 4HS
    ushort_t* W2T   = (ushort_t*)(ws + SZ + 13 * HS);   // 4HS
    ushort_t* WhT   = (ushort_t*)(ws + SZ + 17 * HS);   // 0.25HS

    const size_t qkvZ = (size_t)1536 * 512;
    dim3 b256(256);
    wt_kernel<<<dim3(16, 16, NL), b256, 0, stream>>>(Wq, WqkvT, D, D, (size_t)D * D, qkvZ);
    wt_kernel<<<dim3(16, 16, NL), b256, 0, stream>>>(Wk, WqkvT + 512 * 512, D, D, (size_t)D * D, qkvZ);
    wt_kernel<<<dim3(16, 16, NL), b256, 0, stream>>>(Wv, WqkvT + 1024 * 512, D, D, (size_t)D * D, qkvZ);
    wt_kernel<<<dim3(16, 16, NL), b256, 0, stream>>>(Wp, WpT, D, D, (size_t)D * D, (size_t)D * D);
    wt_kernel<<<dim3(64, 16, NL), b256, 0, stream>>>(W1, W1T, D, 4 * D, (size_t)D * 4 * D, (size_t)D * 4 * D);
    wt_kernel<<<dim3(16, 64, NL), b256, 0, stream>>>(W2, W2T, 4 * D, D, (size_t)4 * D * D, (size_t)4 * D * D);
    wt_kernel<<<dim3(16, 16, 1), b256, 0, stream>>>(Whead, WhT, D, D, 0, 0);

    add_pos_kernel<<<(T * D + 255) / 256, b256, 0, stream>>>(seq, pos, X, T * D);

    for (int l = 0; l < NL; ++l) {
        size_t wo = (size_t)l * D * D;
        size_t wo1 = (size_t)l * D * 4 * D;
        layernorm_kernel<<<T, b256, 0, stream>>>(X, ln1w + l * D, ln1b + l * D, Hb);
        gemm_qkv_kernel<<<dim3(24, T / GBM), b256, 0, stream>>>(
            Hb, WqkvT + l * qkvZ, bq + l * D, bk + l * D, bv + l * D, Qb, Kb, Vt);
        flash_attn_kernel<<<dim3(T / QBLK, NH), b256, 0, stream>>>(Qb, Kb, Vt, Yb);
        gemm_bf16_kernel<<<dim3(D / GBN, T / GBM), b256, 0, stream>>>(
            Yb, WpT + wo, bp + l * D, X, X, T, D, D, MODE_F32);
        layernorm_kernel<<<T, b256, 0, stream>>>(X, ln2w + l * D, ln2b + l * D, Hb);
        gemm_bf16_kernel<<<dim3(4 * D / GBN, T / GBM), b256, 0, stream>>>(
            Hb, W1T + wo1, b1 + l * 4 * D, nullptr, M1, T, D, 4 * D, MODE_BF16_GELU);
        gemm_bf16_kernel<<<dim3(D / GBN, T / GBM), b256, 0, stream>>>(
            M1, W2T + wo1, b2 + l * D, X, X, T, 4 * D, D, MODE_F32);
    }
    layernorm_kernel<<<T, b256, 0, stream>>>(X, lnfw, lnfb, Hb);
    gemm_bf16_kernel<<<dim3(D / GBN, T / GBM), b256, 0, stream>>>(
        Hb, WhT, nullptr, nullptr, out, T, D, D, MODE_F32);
}

// Round 10
// 567.380 us; speedup vs baseline: 20.5190x; 1.0293x over previous
//
#include <hip/hip_runtime.h>
#include <math.h>

#define T 2048
#define D 512
#define NH 8
#define DH 64
#define NL 4

typedef float f32x4 __attribute__((ext_vector_type(4)));
typedef short bf16x8 __attribute__((ext_vector_type(8)));
typedef unsigned short u16x4 __attribute__((ext_vector_type(4)));
typedef unsigned int u32x4 __attribute__((ext_vector_type(4)));
typedef unsigned short ushort_t;

#define MODE_F32 0
#define MODE_BF16_GELU 1

__device__ inline ushort_t f2bf(float x) {
    unsigned int u = __float_as_uint(x);
    unsigned int r = (u + 0x7FFFu + ((u >> 16) & 1u)) >> 16;  // RNE
    return (ushort_t)r;
}

__global__ void add_pos_kernel(const float* __restrict__ seq,
                               const float* __restrict__ pos,
                               float* __restrict__ x, int n) {
    int i = blockIdx.x * blockDim.x + threadIdx.x;
    if (i < n) x[i] = seq[i] + pos[i];
}

// Tiled transpose+convert: W[z·wZ + K×N] fp32 -> Wt[z·dZ + N×K] bf16.
__global__ __launch_bounds__(256) void wt_kernel(
    const float* __restrict__ W, ushort_t* __restrict__ Wt, int K, int N,
    size_t wZ, size_t dZ) {
    __shared__ float tile[32][33];
    int tx = threadIdx.x & 31, ty = threadIdx.x >> 5;  // 32 x 8
    const float* Wz = W + (size_t)blockIdx.z * wZ;
    ushort_t* Wtz = Wt + (size_t)blockIdx.z * dZ;
    int n0 = blockIdx.x * 32, k0 = blockIdx.y * 32;
    #pragma unroll
    for (int i = 0; i < 4; ++i)
        tile[ty + i * 8][tx] = Wz[(size_t)(k0 + ty + i * 8) * N + n0 + tx];
    __syncthreads();
    #pragma unroll
    for (int i = 0; i < 4; ++i)
        Wtz[(size_t)(n0 + ty + i * 8) * K + k0 + tx] = f2bf(tile[tx][ty + i * 8]);
}

// One block (256 threads) per row; writes bf16.
__global__ __launch_bounds__(256) void layernorm_kernel(
    const float* __restrict__ x, const float* __restrict__ w,
    const float* __restrict__ b, ushort_t* __restrict__ out) {
    int row = blockIdx.x;
    int tid = threadIdx.x;
    const float* xr = x + (size_t)row * D;
    float v0 = xr[tid];
    float v1 = xr[tid + 256];
    __shared__ float red[256];
    red[tid] = v0 + v1;
    __syncthreads();
    for (int off = 128; off > 0; off >>= 1) {
        if (tid < off) red[tid] += red[tid + off];
        __syncthreads();
    }
    float mu = red[0] * (1.0f / D);
    __syncthreads();
    float d0 = v0 - mu, d1 = v1 - mu;
    red[tid] = d0 * d0 + d1 * d1;
    __syncthreads();
    for (int off = 128; off > 0; off >>= 1) {
        if (tid < off) red[tid] += red[tid + off];
        __syncthreads();
    }
    float rstd = rsqrtf(red[0] * (1.0f / D) + 1e-5f);
    out[(size_t)row * D + tid]       = f2bf(d0 * rstd * w[tid]       + b[tid]);
    out[(size_t)row * D + tid + 256] = f2bf(d1 * rstd * w[tid + 256] + b[tid + 256]);
}

// Generic GEMM: C = mode( A[M,K](bf16) @ Wt[N,K](bf16) + bias (+resid) )
// 64x64 tile, BK=64, double-buffered LDS, 1 barrier/iter, reg prefetch.
#define GBM 64
#define GBN 64
#define GBK 64
#define LDG 72  // bf16 elems per row: 144B, 16B-aligned
__global__ __launch_bounds__(256) void gemm_bf16_kernel(
    const ushort_t* __restrict__ A, const ushort_t* __restrict__ Wt,
    const float* __restrict__ bias, const float* __restrict__ resid,
    void* __restrict__ Cout, int M, int K, int N, int mode) {
    __shared__ __align__(16) ushort_t As[2][GBM][LDG];
    __shared__ __align__(16) ushort_t Bs[2][GBN][LDG];
    int tid = threadIdx.x;
    int lane = tid & 63;
    int w = tid >> 6;
    int wr = w >> 1, wc = w & 1;
    int rowBase = blockIdx.y * GBM, colBase = blockIdx.x * GBN;
    int half = lane >> 4;
    int r16 = lane & 15;
    int sr = tid >> 2, sc = (tid & 3) * 16;

    const ushort_t* Arow = A + (size_t)(rowBase + sr) * K + sc;
    const ushort_t* Brow = Wt + (size_t)(colBase + sr) * K + sc;
    bf16x8 a0 = *(const bf16x8*)Arow, a1 = *(const bf16x8*)(Arow + 8);
    bf16x8 b0 = *(const bf16x8*)Brow, b1 = *(const bf16x8*)(Brow + 8);

    f32x4 acc[2][2];
    #pragma unroll
    for (int i = 0; i < 2; ++i)
        #pragma unroll
        for (int j = 0; j < 2; ++j)
            acc[i][j] = (f32x4){0.f, 0.f, 0.f, 0.f};

    int nIter = K / GBK;
    for (int it = 0; it < nIter; ++it) {
        int buf = it & 1;
        *(bf16x8*)&As[buf][sr][sc]     = a0;
        *(bf16x8*)&As[buf][sr][sc + 8] = a1;
        *(bf16x8*)&Bs[buf][sr][sc]     = b0;
        *(bf16x8*)&Bs[buf][sr][sc + 8] = b1;
        __syncthreads();
        if (it + 1 < nIter) {
            const ushort_t* An = Arow + (it + 1) * GBK;
            const ushort_t* Bn = Brow + (it + 1) * GBK;
            a0 = *(const bf16x8*)An; a1 = *(const bf16x8*)(An + 8);
            b0 = *(const bf16x8*)Bn; b1 = *(const bf16x8*)(Bn + 8);
        }
        #pragma unroll
        for (int ks = 0; ks < 2; ++ks)
            #pragma unroll
            for (int mi = 0; mi < 2; ++mi) {
                bf16x8 af = *(const bf16x8*)&As[buf][wr * 32 + mi * 16 + r16][ks * 32 + half * 8];
                #pragma unroll
                for (int ni = 0; ni < 2; ++ni) {
                    bf16x8 bfv = *(const bf16x8*)&Bs[buf][wc * 32 + ni * 16 + r16][ks * 32 + half * 8];
                    acc[mi][ni] = __builtin_amdgcn_mfma_f32_16x16x32_bf16(af, bfv, acc[mi][ni], 0, 0, 0);
                }
            }
    }
    #pragma unroll
    for (int mi = 0; mi < 2; ++mi) {
        #pragma unroll
        for (int ni = 0; ni < 2; ++ni) {
            int col = colBase + wc * 32 + ni * 16 + r16;
            float bc = bias ? bias[col] : 0.f;
            #pragma unroll
            for (int j = 0; j < 4; ++j) {
                int row = rowBase + wr * 32 + mi * 16 + half * 4 + j;
                float v = acc[mi][ni][j] + bc;
                if (mode == MODE_F32) {
                    if (resid) v += resid[(size_t)row * N + col];
                    ((float*)Cout)[(size_t)row * N + col] = v;
                } else {  // MODE_BF16_GELU
                    v = 0.5f * v * (1.0f + erff(v * 0.70710678118f));
                    ((ushort_t*)Cout)[(size_t)row * N + col] = f2bf(v);
                }
            }
        }
    }
}

// Fused QKV GEMM: A[T,512] @ Wqkv^T[1536,512] + bias, segmented epilogue:
// cols 0-511 -> Q (x0.125, bf16), 512-1023 -> K (bf16), 1024-1535 -> V^T.
__global__ __launch_bounds__(256) void gemm_qkv_kernel(
    const ushort_t* __restrict__ A, const ushort_t* __restrict__ Wt,
    const float* __restrict__ bq, const float* __restrict__ bk,
    const float* __restrict__ bv, ushort_t* __restrict__ Qb,
    ushort_t* __restrict__ Kb, ushort_t* __restrict__ Vt) {
    __shared__ __align__(16) ushort_t As[2][GBM][LDG];
    __shared__ __align__(16) ushort_t Bs[2][GBN][LDG];
    int tid = threadIdx.x;
    int lane = tid & 63;
    int w = tid >> 6;
    int wr = w >> 1, wc = w & 1;
    int rowBase = blockIdx.y * GBM, colBase = blockIdx.x * GBN;
    int half = lane >> 4;
    int r16 = lane & 15;
    int sr = tid >> 2, sc = (tid & 3) * 16;

    const ushort_t* Arow = A + (size_t)(rowBase + sr) * D + sc;
    const ushort_t* Brow = Wt + (size_t)(colBase + sr) * D + sc;
    bf16x8 a0 = *(const bf16x8*)Arow, a1 = *(const bf16x8*)(Arow + 8);
    bf16x8 b0 = *(const bf16x8*)Brow, b1 = *(const bf16x8*)(Brow + 8);

    f32x4 acc[2][2];
    #pragma unroll
    for (int i = 0; i < 2; ++i)
        #pragma unroll
        for (int j = 0; j < 2; ++j)
            acc[i][j] = (f32x4){0.f, 0.f, 0.f, 0.f};

    const int nIter = D / GBK;  // 8
    for (int it = 0; it < nIter; ++it) {
        int buf = it & 1;
        *(bf16x8*)&As[buf][sr][sc]     = a0;
        *(bf16x8*)&As[buf][sr][sc + 8] = a1;
        *(bf16x8*)&Bs[buf][sr][sc]     = b0;
        *(bf16x8*)&Bs[buf][sr][sc + 8] = b1;
        __syncthreads();
        if (it + 1 < nIter) {
            const ushort_t* An = Arow + (it + 1) * GBK;
            const ushort_t* Bn = Brow + (it + 1) * GBK;
            a0 = *(const bf16x8*)An; a1 = *(const bf16x8*)(An + 8);
            b0 = *(const bf16x8*)Bn; b1 = *(const bf16x8*)(Bn + 8);
        }
        #pragma unroll
        for (int ks = 0; ks < 2; ++ks)
            #pragma unroll
            for (int mi = 0; mi < 2; ++mi) {
                bf16x8 af = *(const bf16x8*)&As[buf][wr * 32 + mi * 16 + r16][ks * 32 + half * 8];
                #pragma unroll
                for (int ni = 0; ni < 2; ++ni) {
                    bf16x8 bfv = *(const bf16x8*)&Bs[buf][wc * 32 + ni * 16 + r16][ks * 32 + half * 8];
                    acc[mi][ni] = __builtin_amdgcn_mfma_f32_16x16x32_bf16(af, bfv, acc[mi][ni], 0, 0, 0);
                }
            }
    }
    int seg = colBase >> 9;          // 0:Q 1:K 2:V (block-uniform)
    int lcolB = (colBase & 511) + wc * 32;
    #pragma unroll
    for (int mi = 0; mi < 2; ++mi) {
        #pragma unroll
        for (int ni = 0; ni < 2; ++ni) {
            int col = lcolB + ni * 16 + r16;
            int row0 = rowBase + wr * 32 + mi * 16 + half * 4;
            if (seg == 0) {
                float bc = bq[col];
                #pragma unroll
                for (int j = 0; j < 4; ++j)
                    Qb[(size_t)(row0 + j) * D + col] = f2bf((acc[mi][ni][j] + bc) * 0.125f);
            } else if (seg == 1) {
                float bc = bk[col];
                #pragma unroll
                for (int j = 0; j < 4; ++j)
                    Kb[(size_t)(row0 + j) * D + col] = f2bf(acc[mi][ni][j] + bc);
            } else {
                float bc = bv[col];
                u16x4 p;
                #pragma unroll
                for (int j = 0; j < 4; ++j) p[j] = f2bf(acc[mi][ni][j] + bc);
                *(u16x4*)&Vt[(size_t)col * T + row0] = p;
            }
        }
    }
}

// Fused flash attention, swapped-operand softmax (each lane owns one q-row).
// S^T = mfma(K,Q): lane(r16,half) holds S[q=r16][k=ni*16+half*4+reg].
// O^T = mfma(V^T,P): lane holds O[q=r16][d=ni*16+half*4+reg]; m/l lane-local.
#define QBLK 64
#define JBLK 64
#define APAD 72
__global__ __launch_bounds__(256) void flash_attn_kernel(
    const ushort_t* __restrict__ Q, const ushort_t* __restrict__ Kb,
    const ushort_t* __restrict__ Vt, ushort_t* __restrict__ Y) {
    __shared__ __align__(16) ushort_t Qs[QBLK][APAD];     // [q][d]
    __shared__ __align__(16) ushort_t Ks[2][JBLK][APAD];  // [j][d]
    __shared__ __align__(16) ushort_t Vs[2][DH][APAD];    // [d][j]
    int h = blockIdx.y;
    int qBase = blockIdx.x * QBLK;
    int tid = threadIdx.x;
    int lane = tid & 63;
    int w = tid >> 6;
    int r16 = lane & 15;
    int half = lane >> 4;
    int sr = tid >> 2, sc16 = (tid & 3) * 16;

    {
        const ushort_t* src = Q + (size_t)(qBase + sr) * D + h * DH + sc16;
        *(bf16x8*)&Qs[sr][sc16]     = *(const bf16x8*)src;
        *(bf16x8*)&Qs[sr][sc16 + 8] = *(const bf16x8*)(src + 8);
    }
    // prefetch K/V tile 0 into regs
    bf16x8 kr0, kr1, vr0, vr1;
    {
        const ushort_t* ks_ = Kb + (size_t)sr * D + h * DH + sc16;
        const ushort_t* vs_ = Vt + (size_t)(h * DH + sr) * T + sc16;
        kr0 = *(const bf16x8*)ks_; kr1 = *(const bf16x8*)(ks_ + 8);
        vr0 = *(const bf16x8*)vs_; vr1 = *(const bf16x8*)(vs_ + 8);
    }
    __syncthreads();
    // hoist Q frags (loop-invariant): B-operand cols = q = r16
    bf16x8 qf0 = *(const bf16x8*)&Qs[w * 16 + r16][half * 8];
    bf16x8 qf1 = *(const bf16x8*)&Qs[w * 16 + r16][32 + half * 8];

    f32x4 o_acc[4];
    #pragma unroll
    for (int i = 0; i < 4; ++i) o_acc[i] = (f32x4){0.f, 0.f, 0.f, 0.f};
    float m_run = -3e38f, l_run = 0.f;

    // PV shuffle sources: values for q-row r16 live on lanes {r16+16*s}
    int srcE = r16 + 32 * (half & 1);
    int srcO = srcE + 16;

    const int NT = T / JBLK;
    for (int jt = 0; jt < NT; ++jt) {
        int buf = jt & 1;
        *(bf16x8*)&Ks[buf][sr][sc16]     = kr0;
        *(bf16x8*)&Ks[buf][sr][sc16 + 8] = kr1;
        *(bf16x8*)&Vs[buf][sr][sc16]     = vr0;
        *(bf16x8*)&Vs[buf][sr][sc16 + 8] = vr1;
        __syncthreads();
        if (jt + 1 < NT) {
            int jB = (jt + 1) * JBLK;
            const ushort_t* ks_ = Kb + (size_t)(jB + sr) * D + h * DH + sc16;
            const ushort_t* vs_ = Vt + (size_t)(h * DH + sr) * T + jB + sc16;
            kr0 = *(const bf16x8*)ks_; kr1 = *(const bf16x8*)(ks_ + 8);
            vr0 = *(const bf16x8*)vs_; vr1 = *(const bf16x8*)(vs_ + 8);
        }
        // S^T(64x16) = K_tile @ Q^T : s[ni][reg] = S[q=r16][k=ni*16+half*4+reg]
        f32x4 s[4];
        #pragma unroll
        for (int ni = 0; ni < 4; ++ni) s[ni] = (f32x4){0.f, 0.f, 0.f, 0.f};
        __builtin_amdgcn_s_setprio(1);
        #pragma unroll
        for (int ni = 0; ni < 4; ++ni) {
            bf16x8 kf0 = *(const bf16x8*)&Ks[buf][ni * 16 + r16][half * 8];
            bf16x8 kf1 = *(const bf16x8*)&Ks[buf][ni * 16 + r16][32 + half * 8];
            s[ni] = __builtin_amdgcn_mfma_f32_16x16x32_bf16(kf0, qf0, s[ni], 0, 0, 0);
            s[ni] = __builtin_amdgcn_mfma_f32_16x16x32_bf16(kf1, qf1, s[ni], 0, 0, 0);
        }
        __builtin_amdgcn_s_setprio(0);
        // lane-local softmax over this tile's 16 scores + cross-half reduce
        float mx = s[0][0];
        #pragma unroll
        for (int ni = 0; ni < 4; ++ni)
            #pragma unroll
            for (int j = 0; j < 4; ++j) mx = fmaxf(mx, s[ni][j]);
        mx = fmaxf(mx, __shfl_xor(mx, 16));
        mx = fmaxf(mx, __shfl_xor(mx, 32));
        float mn = fmaxf(m_run, mx);
        float alpha = __expf(m_run - mn);
        m_run = mn;
        float p[4][4];
        float lsum = 0.f;
        #pragma unroll
        for (int ni = 0; ni < 4; ++ni)
            #pragma unroll
            for (int j = 0; j < 4; ++j) {
                p[ni][j] = __expf(s[ni][j] - mn);
                lsum += p[ni][j];
            }
        lsum += __shfl_xor(lsum, 16);
        lsum += __shfl_xor(lsum, 32);
        l_run = l_run * alpha + lsum;
        #pragma unroll
        for (int ni = 0; ni < 4; ++ni)
            #pragma unroll
            for (int j = 0; j < 4; ++j) o_acc[ni][j] *= alpha;
        // pack P to bf16 pairs: q_lo[ni]={p0,p1}, q_hi[ni]={p2,p3}
        unsigned int q_lo[4], q_hi[4];
        #pragma unroll
        for (int ni = 0; ni < 4; ++ni) {
            q_lo[ni] = (unsigned)f2bf(p[ni][0]) | ((unsigned)f2bf(p[ni][1]) << 16);
            q_hi[ni] = (unsigned)f2bf(p[ni][2]) | ((unsigned)f2bf(p[ni][3]) << 16);
        }
        // PV swapped: O^T += V^T(64d x 64j) @ P^T ; B-frag built via shuffles
        #pragma unroll
        for (int ks = 0; ks < 2; ++ks) {
            unsigned a0 = __shfl((int)q_lo[2 * ks], srcE);
            unsigned a1 = __shfl((int)q_hi[2 * ks], srcE);
            unsigned b0 = __shfl((int)q_lo[2 * ks], srcO);
            unsigned b1 = __shfl((int)q_hi[2 * ks], srcO);
            unsigned c0 = __shfl((int)q_lo[2 * ks + 1], srcE);
            unsigned c1 = __shfl((int)q_hi[2 * ks + 1], srcE);
            unsigned d0 = __shfl((int)q_lo[2 * ks + 1], srcO);
            unsigned d1 = __shfl((int)q_hi[2 * ks + 1], srcO);
            u32x4 fp;
            fp[0] = (half < 2) ? a0 : c0;
            fp[1] = (half < 2) ? a1 : c1;
            fp[2] = (half < 2) ? b0 : d0;
            fp[3] = (half < 2) ? b1 : d1;
            bf16x8 pb = __builtin_bit_cast(bf16x8, fp);
            __builtin_amdgcn_s_setprio(1);
            #pragma unroll
            for (int ni = 0; ni < 4; ++ni) {
                bf16x8 vf = *(const bf16x8*)&Vs[buf][ni * 16 + r16][ks * 32 + half * 8];
                o_acc[ni] = __builtin_amdgcn_mfma_f32_16x16x32_bf16(vf, pb, o_acc[ni], 0, 0, 0);
            }
            __builtin_amdgcn_s_setprio(0);
        }
    }
    // epilogue: lane holds O[q = qBase+w*16+r16][d = ni*16+half*4+reg]
    float inv = 1.0f / l_run;
    int qrow = qBase + w * 16 + r16;
    #pragma unroll
    for (int ni = 0; ni < 4; ++ni) {
        u16x4 pk;
        #pragma unroll
        for (int j = 0; j < 4; ++j) pk[j] = f2bf(o_acc[ni][j] * inv);
        *(u16x4*)&Y[(size_t)qrow * D + h * DH + ni * 16 + half * 4] = pk;
    }
}

extern "C" void kernel_launch(void* const* d_in, const int* in_sizes, int n_in,
                              void* d_out, int out_size, void* d_ws, size_t ws_size,
                              hipStream_t stream) {
    const float* seq  = (const float*)d_in[0];
    const float* pos  = (const float*)d_in[1];
    const float* Wq   = (const float*)d_in[2];
    const float* bq   = (const float*)d_in[3];
    const float* Wk   = (const float*)d_in[4];
    const float* bk   = (const float*)d_in[5];
    const float* Wv   = (const float*)d_in[6];
    const float* bv   = (const float*)d_in[7];
    const float* Wp   = (const float*)d_in[8];
    const float* bp   = (const float*)d_in[9];
    const float* W1   = (const float*)d_in[10];
    const float* b1   = (const float*)d_in[11];
    const float* W2   = (const float*)d_in[12];
    const float* b2   = (const float*)d_in[13];
    const float* ln1w = (const float*)d_in[14];
    const float* ln1b = (const float*)d_in[15];
    const float* ln2w = (const float*)d_in[16];
    const float* ln2b = (const float*)d_in[17];
    const float* lnfw = (const float*)d_in[18];
    const float* lnfb = (const float*)d_in[19];
    const float* Whead = (const float*)d_in[20];
    float* out = (float*)d_out;

    float* ws = (float*)d_ws;
    const size_t SZ = (size_t)T * D;   // 1,048,576 floats
    const size_t HS = SZ / 2;          // one bf16 T*D buffer, in float units
    float*    X     = ws;                               // [0, SZ)
    ushort_t* Hb    = (ushort_t*)(ws + SZ);             // +HS
    ushort_t* Qb    = (ushort_t*)(ws + SZ + HS);        // +HS
    ushort_t* Kb    = (ushort_t*)(ws + SZ + 2 * HS);    // +HS
    ushort_t* Vt    = (ushort_t*)(ws + SZ + 3 * HS);    // +HS
    ushort_t* Yb    = (ushort_t*)(ws + SZ + 4 * HS);    // +HS
    ushort_t* M1    = Qb;  // T x 4D bf16, aliases Qb..Yb (dead by then)
    ushort_t* WqkvT = (ushort_t*)(ws + SZ + 5 * HS);    // NL*1536*512 bf16 = 3HS
    ushort_t* WpT   = (ushort_t*)(ws + SZ + 8 * HS);    // NL*D*D bf16 = 1HS
    ushort_t* W1T   = (ushort_t*)(ws + SZ + 9 * HS);    // NL*D*4D bf16 = 4HS
    ushort_t* W2T   = (ushort_t*)(ws + SZ + 13 * HS);   // 4HS
    ushort_t* WhT   = (ushort_t*)(ws + SZ + 17 * HS);   // 0.25HS

    const size_t qkvZ = (size_t)1536 * 512;
    dim3 b256(256);
    wt_kernel<<<dim3(16, 16, NL), b256, 0, stream>>>(Wq, WqkvT, D, D, (size_t)D * D, qkvZ);
    wt_kernel<<<dim3(16, 16, NL), b256, 0, stream>>>(Wk, WqkvT + 512 * 512, D, D, (size_t)D * D, qkvZ);
    wt_kernel<<<dim3(16, 16, NL), b256, 0, stream>>>(Wv, WqkvT + 1024 * 512, D, D, (size_t)D * D, qkvZ);
    wt_kernel<<<dim3(16, 16, NL), b256, 0, stream>>>(Wp, WpT, D, D, (size_t)D * D, (size_t)D * D);
    wt_kernel<<<dim3(64, 16, NL), b256, 0, stream>>>(W1, W1T, D, 4 * D, (size_t)D * 4 * D, (size_t)D * 4 * D);
    wt_kernel<<<dim3(16, 64, NL), b256, 0, stream>>>(W2, W2T, 4 * D, D, (size_t)4 * D * D, (size_t)4 * D * D);
    wt_kernel<<<dim3(16, 16, 1), b256, 0, stream>>>(Whead, WhT, D, D, 0, 0);

    add_pos_kernel<<<(T * D + 255) / 256, b256, 0, stream>>>(seq, pos, X, T * D);

    for (int l = 0; l < NL; ++l) {
        size_t wo = (size_t)l * D * D;
        size_t wo1 = (size_t)l * D * 4 * D;
        layernorm_kernel<<<T, b256, 0, stream>>>(X, ln1w + l * D, ln1b + l * D, Hb);
        gemm_qkv_kernel<<<dim3(24, T / GBM), b256, 0, stream>>>(
            Hb, WqkvT + l * qkvZ, bq + l * D, bk + l * D, bv + l * D, Qb, Kb, Vt);
        flash_attn_kernel<<<dim3(T / QBLK, NH), b256, 0, stream>>>(Qb, Kb, Vt, Yb);
        gemm_bf16_kernel<<<dim3(D / GBN, T / GBM), b256, 0, stream>>>(
            Yb, WpT + wo, bp + l * D, X, X, T, D, D, MODE_F32);
        layernorm_kernel<<<T, b256, 0, stream>>>(X, ln2w + l * D, ln2b + l * D, Hb);
        gemm_bf16_kernel<<<dim3(4 * D / GBN, T / GBM), b256, 0, stream>>>(
            Hb, W1T + wo1, b1 + l * 4 * D, nullptr, M1, T, D, 4 * D, MODE_BF16_GELU);
        gemm_bf16_kernel<<<dim3(D / GBN, T / GBM), b256, 0, stream>>>(
            M1, W2T + wo1, b2 + l * D, X, X, T, 4 * D, D, MODE_F32);
    }
    layernorm_kernel<<<T, b256, 0, stream>>>(X, lnfw, lnfb, Hb);
    gemm_bf16_kernel<<<dim3(D / GBN, T / GBM), b256, 0, stream>>>(
        Hb, WhT, nullptr, nullptr, out, T, D, D, MODE_F32);
}